// Round 11
// baseline (1382.519 us; speedup 1.0000x reference)
//
#include <hip/hip_runtime.h>
#include <stdint.h>

typedef __attribute__((ext_vector_type(4))) int int4v;

// ---------- helpers ----------

__device__ __forceinline__ int pack4_rn(float4 v, float s) {
    int a = __float2int_rn(v.x * s) & 0xff;
    int b = __float2int_rn(v.y * s) & 0xff;
    int c = __float2int_rn(v.z * s) & 0xff;
    int d = __float2int_rn(v.w * s) & 0xff;
    return a | (b << 8) | (c << 16) | (d << 24);
}

__device__ __forceinline__ int bin4(float4 v) {
    int a = (v.x > 0.5f) ? 1 : 0;
    int b = (v.y > 0.5f) ? 1 : 0;
    int c = (v.z > 0.5f) ? 1 : 0;
    int d = (v.w > 0.5f) ? 1 : 0;
    return a | (b << 8) | (c << 16) | (d << 24);
}

// ---------- pre-pass: x (f32) -> per-row-quantized i8 + rscale ----------
// (measured at BW floor; unchanged since R6)

__global__ __launch_bounds__(256) void lb_quant_x(const float* __restrict__ x,
        signed char* __restrict__ xq, float* __restrict__ rscale, int K)
{
    const int row = blockIdx.x;
    const int tid = threadIdx.x;
    const float* xr = x + (size_t)row * K;

    float mx = 0.f;
    for (int i = tid * 4; i < K; i += 256 * 4) {
        float4 v = *(const float4*)(xr + i);
        mx = fmaxf(mx, fmaxf(fmaxf(fabsf(v.x), fabsf(v.y)),
                             fmaxf(fabsf(v.z), fabsf(v.w))));
    }
#pragma unroll
    for (int s = 32; s; s >>= 1) mx = fmaxf(mx, __shfl_xor(mx, s));
    __shared__ float wmax[4];
    if ((tid & 63) == 0) wmax[tid >> 6] = mx;
    __syncthreads();
    mx = fmaxf(fmaxf(wmax[0], wmax[1]), fmaxf(wmax[2], wmax[3]));

    const float s = (mx > 0.f) ? 127.f / mx : 0.f;
    if (tid == 0) rscale[row] = (mx > 0.f) ? mx * (1.f / 127.f) : 0.f;

    for (int i = tid * 16; i < K; i += 256 * 16) {
        float4 a = *(const float4*)(xr + i);
        float4 b = *(const float4*)(xr + i + 4);
        float4 c = *(const float4*)(xr + i + 8);
        float4 d = *(const float4*)(xr + i + 12);
        int4 o;
        o.x = pack4_rn(a, s); o.y = pack4_rn(b, s);
        o.z = pack4_rn(c, s); o.w = pack4_rn(d, s);
        *(int4*)(xq + (size_t)row * K + i) = o;
    }
}

// ---------- pre-pass: w (f32) -> binarized i8 {0,1} ----------

__global__ void lb_bin_w8(const float* __restrict__ w, int4* __restrict__ wq, long n16) {
    long i = (long)blockIdx.x * blockDim.x + threadIdx.x;
    long stride = (long)gridDim.x * blockDim.x;
    for (; i < n16; i += stride) {
        const float4* p = (const float4*)w + i * 4;
        float4 v0 = p[0], v1 = p[1], v2 = p[2], v3 = p[3];
        int4 o;
        o.x = bin4(v0); o.y = bin4(v1); o.z = bin4(v2); o.w = bin4(v3);
        wq[i] = o;
    }
}

// ---------- main GEMM (i8, 16x16x64): 256x256, BK=64, DOUBLE-buffered ----------
// KEY CHANGE vs R6 (quad-buffer, 1 block/CU): double-buffer = 64 KiB LDS ->
// 2 blocks/CU co-resident (4 waves/SIMD). Two independent barrier domains
// de-phase, so one block's 32-MFMA clusters cover the other's read/barrier
// stalls (m114) while keeping R6's full per-tile amortization.
// Per tile: 12 ds_read_b128 -> lgkm0 + barrier (buf dead) -> stage t+2 (4
// gload_lds, distance-2) -> 32 MFMA (setprio) -> counted vmcnt(4) -> barrier.
// Fragment pattern + granule swizzle are R6-verbatim (0 conflicts, 5 rounds).

#define BM 256
#define BN 256
#define BK 64
#define TBYTES 16384   // bytes per LDS buffer (256 rows x 64 B)

__global__ __launch_bounds__(512, 4) void lb_gemm256_i8(
    const signed char* __restrict__ A,   // M x K i8 (quantized x)
    const signed char* __restrict__ B,   // N x K i8 {0,1} (binarized weight)
    const float* __restrict__ rscale,    // M row dequant scales
    const float* __restrict__ bias,
    float* __restrict__ C,
    int M, int N, int K)
{
    __shared__ signed char ldsA[2 * TBYTES];   // 32 KiB
    __shared__ signed char ldsB[2 * TBYTES];   // 32 KiB

    const int tid  = threadIdx.x;
    const int lane = tid & 63;
    const int wave = tid >> 6;       // 0..7
    const int wr   = wave >> 2;      // 0..1  -> 128 output rows
    const int wc   = wave & 3;       // 0..3  -> 64 output cols

    // XCD-aware bijective swizzle (grid % 8 == 0 guaranteed by launcher)
    int nwg = gridDim.x;
    int bid = blockIdx.x;
    bid = (bid & 7) * (nwg >> 3) + (bid >> 3);

    const int ntiles = N / BN;
    const int brow = (bid / ntiles) * BM;
    const int bcol = (bid % ntiles) * BN;

    const signed char* Abase = A + (size_t)brow * K;
    const signed char* Bbase = B + (size_t)bcol * K;

    // stage one 8 KiB chunk (128 rows x 64 B): linear LDS dest (tid*16),
    // inverse-swizzled global source (slot=(g+(row>>1))&3)
    const int srr = tid >> 2;
    const int sg  = tid & 3;
    auto stage = [&](const signed char* gbase, signed char* lbuf, int kt, int c) {
        int rr = c * 128 + srr;
        int gl = (sg - (rr >> 1)) & 3;
        const signed char* src = gbase + (size_t)rr * K + (size_t)kt * BK + gl * 16;
        signed char* dst = lbuf + c * 8192 + tid * 16;
        __builtin_amdgcn_global_load_lds(
            (const __attribute__((address_space(1))) void*)src,
            (__attribute__((address_space(3))) void*)dst, 16, 0, 0);
    };

    const int fr = lane & 15;
    const int fq = lane >> 4;                 // k-group
    const int sl = (fq + (fr >> 1)) & 3;      // stored slot for this lane

    int4v acc[8][4];
#pragma unroll
    for (int i = 0; i < 8; ++i)
#pragma unroll
        for (int j = 0; j < 4; ++j)
            acc[i][j] = (int4v){0, 0, 0, 0};

    const int nk = K / BK;   // >= 4 (launcher guard)

    // prologue: stage tiles 0 (buf0) and 1 (buf1); certify tile 0
#pragma unroll
    for (int t = 0; t < 2; ++t) {
        stage(Abase, &ldsA[t * TBYTES], t, 0); stage(Abase, &ldsA[t * TBYTES], t, 1);
        stage(Bbase, &ldsB[t * TBYTES], t, 0); stage(Bbase, &ldsB[t * TBYTES], t, 1);
    }
    asm volatile("s_waitcnt vmcnt(4)" ::: "memory");
    __builtin_amdgcn_s_barrier();

    int4v af[8], bf[4];

    for (int t = 0; t < nk; ++t) {
        const int p = t & 1;
        const signed char* ap = &ldsA[p * TBYTES + (wr * 128 + fr) * 64];
        const signed char* bp = &ldsB[p * TBYTES + (wc * 64 + fr) * 64];

        // read this tile's 12 fragments (R6 pattern, 0 conflicts)
#pragma unroll
        for (int m = 0; m < 8; ++m) af[m] = *(const int4v*)(ap + m * 1024 + sl * 16);
#pragma unroll
        for (int n = 0; n < 4; ++n) bf[n] = *(const int4v*)(bp + n * 1024 + sl * 16);
        asm volatile("s_waitcnt lgkmcnt(0)" ::: "memory");
        __builtin_amdgcn_sched_barrier(0);
        __builtin_amdgcn_s_barrier();          // all reads done -> buf p dead

        // stage tile t+2 into the just-freed buffer (distance-2)
        if (t + 2 < nk) {
            stage(Abase, &ldsA[p * TBYTES], t + 2, 0);
            stage(Abase, &ldsA[p * TBYTES], t + 2, 1);
            stage(Bbase, &ldsB[p * TBYTES], t + 2, 0);
            stage(Bbase, &ldsB[p * TBYTES], t + 2, 1);
        }

        __builtin_amdgcn_s_setprio(1);
#pragma unroll
        for (int m = 0; m < 8; ++m)
#pragma unroll
            for (int n = 0; n < 4; ++n)
                acc[m][n] = __builtin_amdgcn_mfma_i32_16x16x64_i8(
                    af[m], bf[n], acc[m][n], 0, 0, 0);
        __builtin_amdgcn_s_setprio(0);

        if (t < nk - 1) {
            // certify t+1's 4 loads; leave t+2's 4 in flight (counted)
            if (t + 2 < nk) asm volatile("s_waitcnt vmcnt(4)" ::: "memory");
            else            asm volatile("s_waitcnt vmcnt(0)" ::: "memory");
            __builtin_amdgcn_s_barrier();
        }
    }

    // epilogue: C/D layout col = lane&15, row = (lane>>4)*4 + reg
    float bn[4];
#pragma unroll
    for (int n = 0; n < 4; ++n)
        bn[n] = bias[bcol + wc * 64 + n * 16 + fr];

#pragma unroll
    for (int m = 0; m < 8; ++m) {
#pragma unroll
        for (int j = 0; j < 4; ++j) {
            int row = brow + wr * 128 + m * 16 + fq * 4 + j;
            float rs = rscale[row];
#pragma unroll
            for (int n = 0; n < 4; ++n) {
                int col = bcol + wc * 64 + n * 16 + fr;
                C[(size_t)row * N + col] = (float)acc[m][n][j] * rs + bn[n];
            }
        }
    }
}

// ---------- fallback: correct fp32 tiled GEMM ----------

__global__ __launch_bounds__(256) void lb_gemm_fb(
    const float* __restrict__ x, const float* __restrict__ w,
    const float* __restrict__ bias, float* __restrict__ C,
    int M, int N, int K)
{
    __shared__ float As[16][65];
    __shared__ float Bs[16][65];
    const int tid = threadIdx.x;
    const int tx = tid & 15, ty = tid >> 4;
    const int brow = blockIdx.y * 64, bcol = blockIdx.x * 64;

    float acc[4][4] = {};
    for (int kt = 0; kt < K; kt += 16) {
        for (int i = tid; i < 64 * 16; i += 256) {
            int r = i >> 4, k = i & 15;
            As[k][r] = x[(long)(brow + r) * K + kt + k];
        }
        for (int i = tid; i < 64 * 16; i += 256) {
            int n = i >> 4, k = i & 15;
            Bs[k][n] = (w[(long)(bcol + n) * K + kt + k] > 0.5f) ? 1.f : 0.f;
        }
        __syncthreads();
#pragma unroll
        for (int k = 0; k < 16; ++k) {
            float a[4], b[4];
#pragma unroll
            for (int i = 0; i < 4; ++i) a[i] = As[k][ty * 4 + i];
#pragma unroll
            for (int j = 0; j < 4; ++j) b[j] = Bs[k][tx * 4 + j];
#pragma unroll
            for (int i = 0; i < 4; ++i)
#pragma unroll
                for (int j = 0; j < 4; ++j)
                    acc[i][j] += a[i] * b[j];
        }
        __syncthreads();
    }
#pragma unroll
    for (int i = 0; i < 4; ++i)
#pragma unroll
        for (int j = 0; j < 4; ++j)
            C[(long)(brow + ty * 4 + i) * N + bcol + tx * 4 + j] = acc[i][j] + bias[bcol + tx * 4 + j];
}

// ---------- launcher ----------

extern "C" void kernel_launch(void* const* d_in, const int* in_sizes, int n_in,
                              void* d_out, int out_size, void* d_ws, size_t ws_size,
                              hipStream_t stream) {
    const float* x    = (const float*)d_in[0];
    const float* w    = (const float*)d_in[1];
    const float* bias = (const float*)d_in[2];
    float* out = (float*)d_out;

    const int N = in_sizes[2];                 // 4096
    const int K = in_sizes[1] / N;             // 4096
    const int M = in_sizes[0] / K;             // 8192

    const size_t need = (size_t)M * K + (size_t)N * K + (size_t)M * 4;
    const int ngrid = (M / BM) * (N / BN);     // 32*16 = 512
    const bool ok = (ws_size >= need) && (M % BM == 0) && (N % BN == 0)
                    && (K % BK == 0) && (K / BK >= 4) && (ngrid % 8 == 0);

    if (ok) {
        signed char* xq = (signed char*)d_ws;
        signed char* wq = xq + (size_t)M * K;
        float* rscale   = (float*)(wq + (size_t)N * K);

        lb_quant_x<<<M, 256, 0, stream>>>(x, xq, rscale, K);
        long nw16 = (long)N * K / 16;
        lb_bin_w8<<<2048, 256, 0, stream>>>(w, (int4*)wq, nw16);

        lb_gemm256_i8<<<dim3(ngrid), 512, 0, stream>>>(xq, wq, rscale, bias, out, M, N, K);
    } else {
        dim3 grid(N / 64, M / 64);
        lb_gemm_fb<<<grid, 256, 0, stream>>>(x, w, bias, out, M, N, K);
    }
}

// Round 12
// 206.156 us; speedup vs baseline: 6.7062x; 6.7062x over previous
//
#include <hip/hip_runtime.h>
#include <stdint.h>

typedef __attribute__((ext_vector_type(4))) int int4v;

// ---------- helpers ----------

__device__ __forceinline__ int pack4_rn(float4 v, float s) {
    int a = __float2int_rn(v.x * s) & 0xff;
    int b = __float2int_rn(v.y * s) & 0xff;
    int c = __float2int_rn(v.z * s) & 0xff;
    int d = __float2int_rn(v.w * s) & 0xff;
    return a | (b << 8) | (c << 16) | (d << 24);
}

__device__ __forceinline__ int bin4(float4 v) {
    int a = (v.x > 0.5f) ? 1 : 0;
    int b = (v.y > 0.5f) ? 1 : 0;
    int c = (v.z > 0.5f) ? 1 : 0;
    int d = (v.w > 0.5f) ? 1 : 0;
    return a | (b << 8) | (c << 16) | (d << 24);
}

// ---------- pre-pass: x (f32) -> per-row-quantized i8 + rscale ----------
// (measured at BW floor; unchanged since R6)

__global__ __launch_bounds__(256) void lb_quant_x(const float* __restrict__ x,
        signed char* __restrict__ xq, float* __restrict__ rscale, int K)
{
    const int row = blockIdx.x;
    const int tid = threadIdx.x;
    const float* xr = x + (size_t)row * K;

    float mx = 0.f;
    for (int i = tid * 4; i < K; i += 256 * 4) {
        float4 v = *(const float4*)(xr + i);
        mx = fmaxf(mx, fmaxf(fmaxf(fabsf(v.x), fabsf(v.y)),
                             fmaxf(fabsf(v.z), fabsf(v.w))));
    }
#pragma unroll
    for (int s = 32; s; s >>= 1) mx = fmaxf(mx, __shfl_xor(mx, s));
    __shared__ float wmax[4];
    if ((tid & 63) == 0) wmax[tid >> 6] = mx;
    __syncthreads();
    mx = fmaxf(fmaxf(wmax[0], wmax[1]), fmaxf(wmax[2], wmax[3]));

    const float s = (mx > 0.f) ? 127.f / mx : 0.f;
    if (tid == 0) rscale[row] = (mx > 0.f) ? mx * (1.f / 127.f) : 0.f;

    for (int i = tid * 16; i < K; i += 256 * 16) {
        float4 a = *(const float4*)(xr + i);
        float4 b = *(const float4*)(xr + i + 4);
        float4 c = *(const float4*)(xr + i + 8);
        float4 d = *(const float4*)(xr + i + 12);
        int4 o;
        o.x = pack4_rn(a, s); o.y = pack4_rn(b, s);
        o.z = pack4_rn(c, s); o.w = pack4_rn(d, s);
        *(int4*)(xq + (size_t)row * K + i) = o;
    }
}

// ---------- pre-pass: w (f32) -> binarized i8 {0,1} ----------

__global__ void lb_bin_w8(const float* __restrict__ w, int4* __restrict__ wq, long n16) {
    long i = (long)blockIdx.x * blockDim.x + threadIdx.x;
    long stride = (long)gridDim.x * blockDim.x;
    for (; i < n16; i += stride) {
        const float4* p = (const float4*)w + i * 4;
        float4 v0 = p[0], v1 = p[1], v2 = p[2], v3 = p[3];
        int4 o;
        o.x = bin4(v0); o.y = bin4(v1); o.z = bin4(v2); o.w = bin4(v3);
        wq[i] = o;
    }
}

// ---------- main GEMM (i8, 16x16x64): 256x256, BK=128, double-buffered ------
// R6 structure, BK doubled: 64 MFMA per sync-pair per wave (vs 32) so the
// ~constant per-tile sync overhead (reads-drain + 2 barriers + vmcnt) is
// amortized over 2x the math. LDS unchanged at 128 KiB (2 bufs x 32 KB x 2).
// Regs: frags 24 int4v (96 VGPR) + acc 128 AGPR ~= 244 < 256 at
// launch_bounds(512,2) -- no forced spill (R11 lesson: WRITE_SIZE is the
// spill tripwire). Row = 128 B = 8 granules; swizzle slot=(g+(row>>1))&7,
// inverse on gload source / forward on ds_read (same 2-way-free profile).
// Per tile: 24 ds_read_b128 -> lgkm0+barrier (buf dead) -> stage t+2 (8
// gload_lds) -> 64 MFMA (setprio) -> counted vmcnt(8) -> barrier.

#define BM 256
#define BN 256
#define BK 128
#define TBYTES 32768   // bytes per LDS buffer (256 rows x 128 B)

__global__ __launch_bounds__(512, 2) void lb_gemm256_i8(
    const signed char* __restrict__ A,   // M x K i8 (quantized x)
    const signed char* __restrict__ B,   // N x K i8 {0,1} (binarized weight)
    const float* __restrict__ rscale,    // M row dequant scales
    const float* __restrict__ bias,
    float* __restrict__ C,
    int M, int N, int K)
{
    __shared__ signed char ldsA[2 * TBYTES];   // 64 KiB
    __shared__ signed char ldsB[2 * TBYTES];   // 64 KiB

    const int tid  = threadIdx.x;
    const int lane = tid & 63;
    const int wave = tid >> 6;       // 0..7
    const int wr   = wave >> 2;      // 0..1  -> 128 output rows
    const int wc   = wave & 3;       // 0..3  -> 64 output cols

    // XCD-aware bijective swizzle (grid % 8 == 0 guaranteed by launcher)
    int nwg = gridDim.x;
    int bid = blockIdx.x;
    bid = (bid & 7) * (nwg >> 3) + (bid >> 3);

    const int ntiles = N / BN;
    const int brow = (bid / ntiles) * BM;
    const int bcol = (bid % ntiles) * BN;

    const signed char* Abase = A + (size_t)brow * K;
    const signed char* Bbase = B + (size_t)bcol * K;

    // stage one 8 KiB chunk (64 rows x 128 B): linear LDS dest (tid*16),
    // inverse-swizzled global source (slot=(g+(row>>1))&7)
    const int srr = tid >> 3;        // 0..63 row within chunk
    const int sg  = tid & 7;         // stored slot
    auto stage = [&](const signed char* gbase, signed char* lbuf, int kt, int c) {
        int rr = c * 64 + srr;
        int gl = (sg - (rr >> 1)) & 7;
        const signed char* src = gbase + (size_t)rr * K + (size_t)kt * BK + gl * 16;
        signed char* dst = lbuf + c * 8192 + tid * 16;
        __builtin_amdgcn_global_load_lds(
            (const __attribute__((address_space(1))) void*)src,
            (__attribute__((address_space(3))) void*)dst, 16, 0, 0);
    };

    const int fr = lane & 15;
    const int fq = lane >> 4;                 // k-quarter within 64-k subtile

    int4v acc[8][4];
#pragma unroll
    for (int i = 0; i < 8; ++i)
#pragma unroll
        for (int j = 0; j < 4; ++j)
            acc[i][j] = (int4v){0, 0, 0, 0};

    const int nk = K / BK;   // = 32 (launcher guard: >= 4)

    // prologue: stage tiles 0 (buf0) and 1 (buf1), 8 chunks each; certify tile 0
#pragma unroll
    for (int t = 0; t < 2; ++t) {
        stage(Abase, &ldsA[t * TBYTES], t, 0); stage(Abase, &ldsA[t * TBYTES], t, 1);
        stage(Abase, &ldsA[t * TBYTES], t, 2); stage(Abase, &ldsA[t * TBYTES], t, 3);
        stage(Bbase, &ldsB[t * TBYTES], t, 0); stage(Bbase, &ldsB[t * TBYTES], t, 1);
        stage(Bbase, &ldsB[t * TBYTES], t, 2); stage(Bbase, &ldsB[t * TBYTES], t, 3);
    }
    asm volatile("s_waitcnt vmcnt(8)" ::: "memory");
    __builtin_amdgcn_s_barrier();

    int4v af[8][2], bf[4][2];

    for (int t = 0; t < nk; ++t) {
        const int p = t & 1;
        const signed char* ap = &ldsA[p * TBYTES + (wr * 128 + fr) * 128];
        const signed char* bp = &ldsB[p * TBYTES + (wc * 64 + fr) * 128];

        // read this tile's 24 fragments (kk = k-subtile 0/1; granule kk*4+fq)
#pragma unroll
        for (int m = 0; m < 8; ++m) {
#pragma unroll
            for (int kk = 0; kk < 2; ++kk) {
                int row = wr * 128 + m * 16 + fr;
                int slot = ((kk * 4 + fq) + (row >> 1)) & 7;
                af[m][kk] = *(const int4v*)(ap + m * 16 * 128 + slot * 16);
            }
        }
#pragma unroll
        for (int n = 0; n < 4; ++n) {
#pragma unroll
            for (int kk = 0; kk < 2; ++kk) {
                int col = wc * 64 + n * 16 + fr;
                int slot = ((kk * 4 + fq) + (col >> 1)) & 7;
                bf[n][kk] = *(const int4v*)(bp + n * 16 * 128 + slot * 16);
            }
        }
        asm volatile("s_waitcnt lgkmcnt(0)" ::: "memory");
        __builtin_amdgcn_sched_barrier(0);
        __builtin_amdgcn_s_barrier();          // all reads done -> buf p dead

        // stage tile t+2 into the just-freed buffer (distance-2)
        if (t + 2 < nk) {
            stage(Abase, &ldsA[p * TBYTES], t + 2, 0);
            stage(Abase, &ldsA[p * TBYTES], t + 2, 1);
            stage(Abase, &ldsA[p * TBYTES], t + 2, 2);
            stage(Abase, &ldsA[p * TBYTES], t + 2, 3);
            stage(Bbase, &ldsB[p * TBYTES], t + 2, 0);
            stage(Bbase, &ldsB[p * TBYTES], t + 2, 1);
            stage(Bbase, &ldsB[p * TBYTES], t + 2, 2);
            stage(Bbase, &ldsB[p * TBYTES], t + 2, 3);
        }

        __builtin_amdgcn_s_setprio(1);
#pragma unroll
        for (int kk = 0; kk < 2; ++kk)
#pragma unroll
            for (int m = 0; m < 8; ++m)
#pragma unroll
                for (int n = 0; n < 4; ++n)
                    acc[m][n] = __builtin_amdgcn_mfma_i32_16x16x64_i8(
                        af[m][kk], bf[n][kk], acc[m][n], 0, 0, 0);
        __builtin_amdgcn_s_setprio(0);

        if (t < nk - 1) {
            // certify t+1's 8 loads; leave t+2's 8 in flight (counted)
            if (t + 2 < nk) asm volatile("s_waitcnt vmcnt(8)" ::: "memory");
            else            asm volatile("s_waitcnt vmcnt(0)" ::: "memory");
            __builtin_amdgcn_s_barrier();
        }
    }

    // epilogue: C/D layout col = lane&15, row = (lane>>4)*4 + reg
    float bn[4];
#pragma unroll
    for (int n = 0; n < 4; ++n)
        bn[n] = bias[bcol + wc * 64 + n * 16 + fr];

#pragma unroll
    for (int m = 0; m < 8; ++m) {
#pragma unroll
        for (int j = 0; j < 4; ++j) {
            int row = brow + wr * 128 + m * 16 + fq * 4 + j;
            float rs = rscale[row];
#pragma unroll
            for (int n = 0; n < 4; ++n) {
                int col = bcol + wc * 64 + n * 16 + fr;
                C[(size_t)row * N + col] = (float)acc[m][n][j] * rs + bn[n];
            }
        }
    }
}

// ---------- fallback: correct fp32 tiled GEMM ----------

__global__ __launch_bounds__(256) void lb_gemm_fb(
    const float* __restrict__ x, const float* __restrict__ w,
    const float* __restrict__ bias, float* __restrict__ C,
    int M, int N, int K)
{
    __shared__ float As[16][65];
    __shared__ float Bs[16][65];
    const int tid = threadIdx.x;
    const int tx = tid & 15, ty = tid >> 4;
    const int brow = blockIdx.y * 64, bcol = blockIdx.x * 64;

    float acc[4][4] = {};
    for (int kt = 0; kt < K; kt += 16) {
        for (int i = tid; i < 64 * 16; i += 256) {
            int r = i >> 4, k = i & 15;
            As[k][r] = x[(long)(brow + r) * K + kt + k];
        }
        for (int i = tid; i < 64 * 16; i += 256) {
            int n = i >> 4, k = i & 15;
            Bs[k][n] = (w[(long)(bcol + n) * K + kt + k] > 0.5f) ? 1.f : 0.f;
        }
        __syncthreads();
#pragma unroll
        for (int k = 0; k < 16; ++k) {
            float a[4], b[4];
#pragma unroll
            for (int i = 0; i < 4; ++i) a[i] = As[k][ty * 4 + i];
#pragma unroll
            for (int j = 0; j < 4; ++j) b[j] = Bs[k][tx * 4 + j];
#pragma unroll
            for (int i = 0; i < 4; ++i)
#pragma unroll
                for (int j = 0; j < 4; ++j)
                    acc[i][j] += a[i] * b[j];
        }
        __syncthreads();
    }
#pragma unroll
    for (int i = 0; i < 4; ++i)
#pragma unroll
        for (int j = 0; j < 4; ++j)
            C[(long)(brow + ty * 4 + i) * N + bcol + tx * 4 + j] = acc[i][j] + bias[bcol + tx * 4 + j];
}

// ---------- launcher ----------

extern "C" void kernel_launch(void* const* d_in, const int* in_sizes, int n_in,
                              void* d_out, int out_size, void* d_ws, size_t ws_size,
                              hipStream_t stream) {
    const float* x    = (const float*)d_in[0];
    const float* w    = (const float*)d_in[1];
    const float* bias = (const float*)d_in[2];
    float* out = (float*)d_out;

    const int N = in_sizes[2];                 // 4096
    const int K = in_sizes[1] / N;             // 4096
    const int M = in_sizes[0] / K;             // 8192

    const size_t need = (size_t)M * K + (size_t)N * K + (size_t)M * 4;
    const int ngrid = (M / BM) * (N / BN);     // 32*16 = 512
    const bool ok = (ws_size >= need) && (M % BM == 0) && (N % BN == 0)
                    && (K % BK == 0) && (K / BK >= 4) && (ngrid % 8 == 0);

    if (ok) {
        signed char* xq = (signed char*)d_ws;
        signed char* wq = xq + (size_t)M * K;
        float* rscale   = (float*)(wq + (size_t)N * K);

        lb_quant_x<<<M, 256, 0, stream>>>(x, xq, rscale, K);
        long nw16 = (long)N * K / 16;
        lb_bin_w8<<<2048, 256, 0, stream>>>(w, (int4*)wq, nw16);

        lb_gemm256_i8<<<dim3(ngrid), 512, 0, stream>>>(xq, wq, rscale, bias, out, M, N, K);
    } else {
        dim3 grid(N / 64, M / 64);
        lb_gemm_fb<<<grid, 256, 0, stream>>>(x, w, bias, out, M, N, K);
    }
}

// Round 13
// 188.868 us; speedup vs baseline: 7.3200x; 1.0915x over previous
//
#include <hip/hip_runtime.h>
#include <stdint.h>

typedef __attribute__((ext_vector_type(4))) int int4v;

// ---------- helpers ----------

__device__ __forceinline__ int pack4_rn(float4 v, float s) {
    int a = __float2int_rn(v.x * s) & 0xff;
    int b = __float2int_rn(v.y * s) & 0xff;
    int c = __float2int_rn(v.z * s) & 0xff;
    int d = __float2int_rn(v.w * s) & 0xff;
    return a | (b << 8) | (c << 16) | (d << 24);
}

__device__ __forceinline__ int bin4(float4 v) {
    int a = (v.x > 0.5f) ? 1 : 0;
    int b = (v.y > 0.5f) ? 1 : 0;
    int c = (v.z > 0.5f) ? 1 : 0;
    int d = (v.w > 0.5f) ? 1 : 0;
    return a | (b << 8) | (c << 16) | (d << 24);
}

// ---------- pre-pass: x (f32) -> per-row-quantized i8 + rscale ----------
// at BW floor (~25 us): reads 128 MB + writes 32 MB

__global__ __launch_bounds__(256) void lb_quant_x(const float* __restrict__ x,
        signed char* __restrict__ xq, float* __restrict__ rscale, int K)
{
    const int row = blockIdx.x;
    const int tid = threadIdx.x;
    const float* xr = x + (size_t)row * K;

    float mx = 0.f;
    for (int i = tid * 4; i < K; i += 256 * 4) {
        float4 v = *(const float4*)(xr + i);
        mx = fmaxf(mx, fmaxf(fmaxf(fabsf(v.x), fabsf(v.y)),
                             fmaxf(fabsf(v.z), fabsf(v.w))));
    }
#pragma unroll
    for (int s = 32; s; s >>= 1) mx = fmaxf(mx, __shfl_xor(mx, s));
    __shared__ float wmax[4];
    if ((tid & 63) == 0) wmax[tid >> 6] = mx;
    __syncthreads();
    mx = fmaxf(fmaxf(wmax[0], wmax[1]), fmaxf(wmax[2], wmax[3]));

    const float s = (mx > 0.f) ? 127.f / mx : 0.f;
    if (tid == 0) rscale[row] = (mx > 0.f) ? mx * (1.f / 127.f) : 0.f;

    for (int i = tid * 16; i < K; i += 256 * 16) {
        float4 a = *(const float4*)(xr + i);
        float4 b = *(const float4*)(xr + i + 4);
        float4 c = *(const float4*)(xr + i + 8);
        float4 d = *(const float4*)(xr + i + 12);
        int4 o;
        o.x = pack4_rn(a, s); o.y = pack4_rn(b, s);
        o.z = pack4_rn(c, s); o.w = pack4_rn(d, s);
        *(int4*)(xq + (size_t)row * K + i) = o;
    }
}

// ---------- pre-pass: w (f32) -> binarized i8 {0,1} ----------

__global__ void lb_bin_w8(const float* __restrict__ w, int4* __restrict__ wq, long n16) {
    long i = (long)blockIdx.x * blockDim.x + threadIdx.x;
    long stride = (long)gridDim.x * blockDim.x;
    for (; i < n16; i += stride) {
        const float4* p = (const float4*)w + i * 4;
        float4 v0 = p[0], v1 = p[1], v2 = p[2], v3 = p[3];
        int4 o;
        o.x = bin4(v0); o.y = bin4(v1); o.z = bin4(v2); o.w = bin4(v3);
        wq[i] = o;
    }
}

// ---------- main GEMM (i8): 256x256, BK=64, quad-buffered, 2 phases/K-tile ----
// EXACT revert to the Round-6 best (GEMM 152 us, MfmaUtil 38, 0 conflicts).
// Quad-buffer LDS (4 x 16 KB x 2 operands = 128 KiB), distance-3 prefetch,
// counted vmcnt(8), granule swizzle slot=(g+(row>>1))&3 inverse-on-source /
// forward-on-read. mfma_i32_16x16x64_i8, exact i32 accum, row-scale dequant.

#define BM 256
#define BN 256
#define BK 64
#define TBYTES 16384   // bytes per LDS buffer (256 rows x 64 B)

#define MFMA16H(MH) do { \
    __builtin_amdgcn_s_setprio(1); \
    _Pragma("unroll") \
    for (int m_ = 0; m_ < 4; ++m_) { \
      _Pragma("unroll") \
      for (int n_ = 0; n_ < 4; ++n_) { \
        acc[(MH)*4+m_][n_] = __builtin_amdgcn_mfma_i32_16x16x64_i8( \
            af[(MH)*4+m_], bf[n_], acc[(MH)*4+m_][n_], 0, 0, 0); \
      } \
    } \
    __builtin_amdgcn_s_setprio(0); \
} while (0)

#define PHASE_SYNC do { \
    __builtin_amdgcn_s_barrier(); \
    asm volatile("s_waitcnt lgkmcnt(0)" ::: "memory"); \
    __builtin_amdgcn_sched_barrier(0); \
} while (0)

__global__ __launch_bounds__(512, 2) void lb_gemm256_i8(
    const signed char* __restrict__ A,   // M x K i8 (quantized x)
    const signed char* __restrict__ B,   // N x K i8 {0,1} (binarized weight)
    const float* __restrict__ rscale,    // M row dequant scales
    const float* __restrict__ bias,
    float* __restrict__ C,
    int M, int N, int K)
{
    __shared__ signed char ldsA[4 * TBYTES];   // 64 KiB
    __shared__ signed char ldsB[4 * TBYTES];   // 64 KiB

    const int tid  = threadIdx.x;
    const int lane = tid & 63;
    const int wave = tid >> 6;       // 0..7
    const int wr   = wave >> 2;      // 0..1  -> 128 output rows
    const int wc   = wave & 3;       // 0..3  -> 64 output cols

    // XCD-aware bijective swizzle (grid % 8 == 0 guaranteed by launcher)
    int nwg = gridDim.x;
    int bid = blockIdx.x;
    bid = (bid & 7) * (nwg >> 3) + (bid >> 3);

    const int ntiles = N / BN;
    const int brow = (bid / ntiles) * BM;
    const int bcol = (bid % ntiles) * BN;

    const signed char* Abase = A + (size_t)brow * K;
    const signed char* Bbase = B + (size_t)bcol * K;

    // stage one 8 KiB chunk (128 rows x 64 B): linear LDS dest (tid*16),
    // inverse-swizzled global source (slot=(g+(row>>1))&3)
    const int srr = tid >> 2;
    const int sg  = tid & 3;
    auto stage = [&](const signed char* gbase, signed char* lbuf, int kt, int c) {
        int rr = c * 128 + srr;
        int gl = (sg - (rr >> 1)) & 3;
        const signed char* src = gbase + (size_t)rr * K + (size_t)kt * BK + gl * 16;
        signed char* dst = lbuf + c * 8192 + tid * 16;
        __builtin_amdgcn_global_load_lds(
            (const __attribute__((address_space(1))) void*)src,
            (__attribute__((address_space(3))) void*)dst, 16, 0, 0);
    };

    const int fr = lane & 15;
    const int fq = lane >> 4;                 // k-group
    const int sl = (fq + (fr >> 1)) & 3;      // stored slot for this lane

    int4v acc[8][4];
#pragma unroll
    for (int i = 0; i < 8; ++i)
#pragma unroll
        for (int j = 0; j < 4; ++j)
            acc[i][j] = (int4v){0, 0, 0, 0};

    const int nk = K / BK;   // >= 4 (launcher guard)

    // prologue: stage tiles 0,1,2 (4 chunks each), certify tile 0
#pragma unroll
    for (int t = 0; t < 3; ++t) {
        stage(Bbase, &ldsB[t * TBYTES], t, 0); stage(Bbase, &ldsB[t * TBYTES], t, 1);
        stage(Abase, &ldsA[t * TBYTES], t, 0); stage(Abase, &ldsA[t * TBYTES], t, 1);
    }
    asm volatile("s_waitcnt vmcnt(8)" ::: "memory");
    __builtin_amdgcn_s_barrier();

    int4v af[8], bf[4];

    for (int t = 0; t < nk; ++t) {
        const int buf = t & 3;
        const signed char* ap = &ldsA[buf * TBYTES + (wr * 128 + fr) * 64];
        const signed char* bp = &ldsB[buf * TBYTES + (wc * 64 + fr) * 64];
        const bool pf = (t + 3 < nk);
        const int sb = (t + 3) & 3;

        // ---- phase A: af[0..3] + bf[0..3] (8 reads); stage B of t+3 ----
#pragma unroll
        for (int m = 0; m < 4; ++m) af[m] = *(const int4v*)(ap + m * 1024 + sl * 16);
#pragma unroll
        for (int n = 0; n < 4; ++n) bf[n] = *(const int4v*)(bp + n * 1024 + sl * 16);
        if (pf) { stage(Bbase, &ldsB[sb * TBYTES], t + 3, 0);
                  stage(Bbase, &ldsB[sb * TBYTES], t + 3, 1); }
        PHASE_SYNC;
        MFMA16H(0);

        // ---- phase B: af[4..7] (4 reads); stage A of t+3; counted vmcnt ----
#pragma unroll
        for (int m = 4; m < 8; ++m) af[m] = *(const int4v*)(ap + m * 1024 + sl * 16);
        if (pf) { stage(Abase, &ldsA[sb * TBYTES], t + 3, 0);
                  stage(Abase, &ldsA[sb * TBYTES], t + 3, 1); }
        if (pf)               asm volatile("s_waitcnt vmcnt(8)" ::: "memory");
        else if (t == nk - 3) asm volatile("s_waitcnt vmcnt(4)" ::: "memory");
        else if (t == nk - 2) asm volatile("s_waitcnt vmcnt(0)" ::: "memory");
        PHASE_SYNC;
        MFMA16H(1);
    }

    // epilogue: C/D layout col = lane&15, row = (lane>>4)*4 + reg (shape-
    // determined, dtype-independent). out = rscale[row]*acc + bias[col].
    float bn[4];
#pragma unroll
    for (int n = 0; n < 4; ++n)
        bn[n] = bias[bcol + wc * 64 + n * 16 + fr];

#pragma unroll
    for (int m = 0; m < 8; ++m) {
#pragma unroll
        for (int j = 0; j < 4; ++j) {
            int row = brow + wr * 128 + m * 16 + fq * 4 + j;
            float rs = rscale[row];
#pragma unroll
            for (int n = 0; n < 4; ++n) {
                int col = bcol + wc * 64 + n * 16 + fr;
                C[(size_t)row * N + col] = (float)acc[m][n][j] * rs + bn[n];
            }
        }
    }
}

// ---------- fallback: correct fp32 tiled GEMM ----------

__global__ __launch_bounds__(256) void lb_gemm_fb(
    const float* __restrict__ x, const float* __restrict__ w,
    const float* __restrict__ bias, float* __restrict__ C,
    int M, int N, int K)
{
    __shared__ float As[16][65];
    __shared__ float Bs[16][65];
    const int tid = threadIdx.x;
    const int tx = tid & 15, ty = tid >> 4;
    const int brow = blockIdx.y * 64, bcol = blockIdx.x * 64;

    float acc[4][4] = {};
    for (int kt = 0; kt < K; kt += 16) {
        for (int i = tid; i < 64 * 16; i += 256) {
            int r = i >> 4, k = i & 15;
            As[k][r] = x[(long)(brow + r) * K + kt + k];
        }
        for (int i = tid; i < 64 * 16; i += 256) {
            int n = i >> 4, k = i & 15;
            Bs[k][n] = (w[(long)(bcol + n) * K + kt + k] > 0.5f) ? 1.f : 0.f;
        }
        __syncthreads();
#pragma unroll
        for (int k = 0; k < 16; ++k) {
            float a[4], b[4];
#pragma unroll
            for (int i = 0; i < 4; ++i) a[i] = As[k][ty * 4 + i];
#pragma unroll
            for (int j = 0; j < 4; ++j) b[j] = Bs[k][tx * 4 + j];
#pragma unroll
            for (int i = 0; i < 4; ++i)
#pragma unroll
                for (int j = 0; j < 4; ++j)
                    acc[i][j] += a[i] * b[j];
        }
        __syncthreads();
    }
#pragma unroll
    for (int i = 0; i < 4; ++i)
#pragma unroll
        for (int j = 0; j < 4; ++j)
            C[(long)(brow + ty * 4 + i) * N + bcol + tx * 4 + j] = acc[i][j] + bias[bcol + tx * 4 + j];
}

// ---------- launcher ----------

extern "C" void kernel_launch(void* const* d_in, const int* in_sizes, int n_in,
                              void* d_out, int out_size, void* d_ws, size_t ws_size,
                              hipStream_t stream) {
    const float* x    = (const float*)d_in[0];
    const float* w    = (const float*)d_in[1];
    const float* bias = (const float*)d_in[2];
    float* out = (float*)d_out;

    const int N = in_sizes[2];                 // 4096
    const int K = in_sizes[1] / N;             // 4096
    const int M = in_sizes[0] / K;             // 8192

    const size_t need = (size_t)M * K + (size_t)N * K + (size_t)M * 4;
    const int ngrid = (M / BM) * (N / BN);     // 32*16 = 512
    const bool ok = (ws_size >= need) && (M % BM == 0) && (N % BN == 0)
                    && (K % BK == 0) && (K / BK >= 4) && (ngrid % 8 == 0);

    if (ok) {
        signed char* xq = (signed char*)d_ws;
        signed char* wq = xq + (size_t)M * K;
        float* rscale   = (float*)(wq + (size_t)N * K);

        lb_quant_x<<<M, 256, 0, stream>>>(x, xq, rscale, K);
        long nw16 = (long)N * K / 16;
        lb_bin_w8<<<2048, 256, 0, stream>>>(w, (int4*)wq, nw16);

        lb_gemm256_i8<<<dim3(ngrid), 512, 0, stream>>>(xq, wq, rscale, bias, out, M, N, K);
    } else {
        dim3 grid(N / 64, M / 64);
        lb_gemm_fb<<<grid, 256, 0, stream>>>(x, w, bias, out, M, N, K);
    }
}